// Round 1
// baseline (7373.705 us; speedup 1.0000x reference)
//
#include <hip/hip_runtime.h>

// ResidualVectorQuantizer: N=262144 rows, D=128, NQ=4 stages, NE=256 codes.
// f32 throughout (argmin fidelity vs f32 reference). Fused 4-stage kernel,
// residual in registers, 2 threads/row.

constexpr int DIM  = 128;
constexpr int NQ   = 4;
constexpr int NE   = 256;
constexpr int HALF = 64;   // dims per thread (2 threads per row)

// ws layout: [0,8) double loss accumulator; [256, 256+NQ*NE*4) c2 table.

__global__ __launch_bounds__(256) void rvq_prep(const float* __restrict__ codebooks,
                                                double* __restrict__ loss_acc,
                                                float* __restrict__ c2) {
    int g = blockIdx.x * blockDim.x + threadIdx.x;
    if (g == 0) *loss_acc = 0.0;
    if (g < NQ * NE) {
        const float* c = codebooks + (size_t)g * DIM;
        float s = 0.f;
        #pragma unroll 4
        for (int k = 0; k < DIM; ++k) s = fmaf(c[k], c[k], s);
        c2[g] = s;
    }
}

__global__ __launch_bounds__(256) void rvq_main(const float* __restrict__ x,
                                                const float* __restrict__ codebooks,
                                                const float* __restrict__ c2g,
                                                float* __restrict__ out_xq,
                                                float* __restrict__ out_idx,
                                                double* __restrict__ loss_acc) {
    __shared__ float c2s[NQ * NE];
    const int tid = threadIdx.x;
    #pragma unroll
    for (int i = 0; i < 4; ++i) c2s[tid + 256 * i] = c2g[tid + 256 * i];
    __syncthreads();

    const int row  = blockIdx.x * 128 + (tid >> 1);
    const int half = tid & 1;
    const float* xrow = x + (size_t)row * DIM + half * HALF;

    float r[HALF];
    #pragma unroll
    for (int k = 0; k < HALF; k += 4) {
        float4 v = *reinterpret_cast<const float4*>(xrow + k);
        r[k] = v.x; r[k + 1] = v.y; r[k + 2] = v.z; r[k + 3] = v.w;
    }

    float lossacc = 0.f;

    #pragma unroll 1
    for (int qi = 0; qi < NQ; ++qi) {
        const float* cb = codebooks + (size_t)qi * NE * DIM;

        // rr = ||residual||^2 (full row; both lanes get identical value)
        float rr = 0.f;
        #pragma unroll
        for (int k = 0; k < HALF; ++k) rr = fmaf(r[k], r[k], rr);
        rr += __shfl_xor(rr, 1);

        float best_d = 3.4e38f;
        int best_j = 0;
        const float* c2q = &c2s[qi * NE];

        #pragma unroll 1
        for (int j = 0; j < NE; ++j) {
            const float4* c4 =
                reinterpret_cast<const float4*>(cb + (size_t)j * DIM + half * HALF);
            float d0 = 0.f, d1 = 0.f, d2 = 0.f, d3 = 0.f;
            #pragma unroll
            for (int k = 0; k < 16; ++k) {
                float4 a = c4[k];
                d0 = fmaf(a.x, r[4 * k + 0], d0);
                d1 = fmaf(a.y, r[4 * k + 1], d1);
                d2 = fmaf(a.z, r[4 * k + 2], d2);
                d3 = fmaf(a.w, r[4 * k + 3], d3);
            }
            float dot = (d0 + d1) + (d2 + d3);
            dot += __shfl_xor(dot, 1);  // both lanes: full-row dot, bitwise identical
            float dist = rr - 2.0f * dot + c2q[j];
            if (dist < best_d) { best_d = dist; best_j = j; }  // first-min tie-break
        }

        // gather chosen code; replicate reference's exact f32 update sequence
        const float* q = cb + (size_t)best_j * DIM + half * HALF;
        float ls = 0.f;
        #pragma unroll
        for (int k = 0; k < HALF; k += 4) {
            float4 qv = *reinterpret_cast<const float4*>(q + k);
            float s0 = qv.x - r[k + 0];
            float s1 = qv.y - r[k + 1];
            float s2 = qv.z - r[k + 2];
            float s3 = qv.w - r[k + 3];
            ls = fmaf(s0, s0, ls); ls = fmaf(s1, s1, ls);
            ls = fmaf(s2, s2, ls); ls = fmaf(s3, s3, ls);
            float qs0 = r[k + 0] + s0;
            float qs1 = r[k + 1] + s1;
            float qs2 = r[k + 2] + s2;
            float qs3 = r[k + 3] + s3;
            r[k + 0] = r[k + 0] - qs0;
            r[k + 1] = r[k + 1] - qs1;
            r[k + 2] = r[k + 2] - qs2;
            r[k + 3] = r[k + 3] - qs3;
        }
        lossacc += ls;
        if (half == 0) out_idx[(size_t)row * NQ + qi] = (float)best_j;
    }

    // x_q = x - r_final (ulp-level equal to sum of quant_st)
    #pragma unroll
    for (int k = 0; k < HALF; k += 4) {
        float4 xv = *reinterpret_cast<const float4*>(xrow + k);
        float4 o;
        o.x = xv.x - r[k + 0];
        o.y = xv.y - r[k + 1];
        o.z = xv.z - r[k + 2];
        o.w = xv.w - r[k + 3];
        *reinterpret_cast<float4*>(out_xq + (size_t)row * DIM + half * HALF + k) = o;
    }

    // loss reduction: wave shuffle -> LDS -> one f64 atomic per block
    #pragma unroll
    for (int off = 32; off > 0; off >>= 1) lossacc += __shfl_down(lossacc, off);
    __shared__ float wsum[4];
    if ((tid & 63) == 0) wsum[tid >> 6] = lossacc;
    __syncthreads();
    if (tid == 0) {
        double t = ((double)wsum[0] + (double)wsum[1]) +
                   ((double)wsum[2] + (double)wsum[3]);
        atomicAdd(loss_acc, t);
    }
}

__global__ void rvq_finalize(const double* __restrict__ loss_acc,
                             float* __restrict__ out_loss) {
    if (threadIdx.x == 0 && blockIdx.x == 0) {
        // mean_loss = 2 * sum(s^2) / (NQ*N*D) = sum / 67108864
        *out_loss = (float)(*loss_acc * (1.0 / 67108864.0));
    }
}

extern "C" void kernel_launch(void* const* d_in, const int* in_sizes, int n_in,
                              void* d_out, int out_size, void* d_ws, size_t ws_size,
                              hipStream_t stream) {
    const float* x  = (const float*)d_in[0];
    const float* cb = (const float*)d_in[1];
    const int N = in_sizes[0] / DIM;  // 262144

    double* loss_acc = (double*)d_ws;
    float*  c2       = (float*)((char*)d_ws + 256);

    float* out_xq   = (float*)d_out;
    float* out_loss = out_xq + (size_t)N * DIM;
    float* out_idx  = out_loss + 1;

    rvq_prep<<<(NQ * NE + 255) / 256, 256, 0, stream>>>(cb, loss_acc, c2);
    rvq_main<<<N / 128, 256, 0, stream>>>(x, cb, c2, out_xq, out_idx, loss_acc);
    rvq_finalize<<<1, 64, 0, stream>>>(loss_acc, out_loss);
}

// Round 2
// 6914.210 us; speedup vs baseline: 1.0665x; 1.0665x over previous
//
#include <hip/hip_runtime.h>

// ResidualVectorQuantizer: N=262144 rows, D=128, NQ=4 stages, NE=256 codes.
// Round 2: 1 thread/row, residual in 128 VGPRs. Codebook accessed at
// wave-uniform addresses -> compiler scalarizes to s_load + FMA-with-SGPR:
// zero vector-memory traffic and zero shuffles in the inner code loop.

constexpr int DIM = 128;
constexpr int NQ  = 4;
constexpr int NE  = 256;

// ws layout: [0,8) double loss accumulator; [256, 256+NQ*NE*4) c2 table.

__global__ __launch_bounds__(256) void rvq_prep(const float* __restrict__ codebooks,
                                                double* __restrict__ loss_acc,
                                                float* __restrict__ c2) {
    int g = blockIdx.x * blockDim.x + threadIdx.x;
    if (g == 0) *loss_acc = 0.0;
    if (g < NQ * NE) {
        const float* c = codebooks + (size_t)g * DIM;
        float s = 0.f;
        #pragma unroll 4
        for (int k = 0; k < DIM; ++k) s = fmaf(c[k], c[k], s);
        c2[g] = s;
    }
}

__global__ __launch_bounds__(256) void rvq_main(const float* __restrict__ x,
                                                const float* __restrict__ codebooks,
                                                const float* __restrict__ c2g,
                                                float* __restrict__ out_xq,
                                                float* __restrict__ out_idx,
                                                double* __restrict__ loss_acc) {
    const int tid = threadIdx.x;
    const int row = blockIdx.x * 256 + tid;
    const float* xrow = x + (size_t)row * DIM;

    float r[DIM];
    #pragma unroll
    for (int k = 0; k < DIM; k += 4) {
        float4 v = *reinterpret_cast<const float4*>(xrow + k);
        r[k] = v.x; r[k + 1] = v.y; r[k + 2] = v.z; r[k + 3] = v.w;
    }

    float lossacc = 0.f;

    #pragma unroll 1
    for (int qi = 0; qi < NQ; ++qi) {
        const float* cb  = codebooks + (size_t)qi * NE * DIM;
        const float* c2q = c2g + qi * NE;

        // rr = ||residual||^2
        float rr0 = 0.f, rr1 = 0.f, rr2 = 0.f, rr3 = 0.f;
        #pragma unroll
        for (int k = 0; k < DIM; k += 4) {
            rr0 = fmaf(r[k + 0], r[k + 0], rr0);
            rr1 = fmaf(r[k + 1], r[k + 1], rr1);
            rr2 = fmaf(r[k + 2], r[k + 2], rr2);
            rr3 = fmaf(r[k + 3], r[k + 3], rr3);
        }
        const float rr = (rr0 + rr1) + (rr2 + rr3);

        float best_d = 3.4e38f;
        int   best_j = 0;

        for (int j = 0; j < NE; ++j) {
            const float* cj = cb + j * DIM;  // wave-uniform address -> s_load
            float a0 = 0.f, a1 = 0.f, a2 = 0.f, a3 = 0.f;
            float a4 = 0.f, a5 = 0.f, a6 = 0.f, a7 = 0.f;
            #pragma unroll
            for (int k = 0; k < DIM; k += 8) {
                a0 = fmaf(cj[k + 0], r[k + 0], a0);
                a1 = fmaf(cj[k + 1], r[k + 1], a1);
                a2 = fmaf(cj[k + 2], r[k + 2], a2);
                a3 = fmaf(cj[k + 3], r[k + 3], a3);
                a4 = fmaf(cj[k + 4], r[k + 4], a4);
                a5 = fmaf(cj[k + 5], r[k + 5], a5);
                a6 = fmaf(cj[k + 6], r[k + 6], a6);
                a7 = fmaf(cj[k + 7], r[k + 7], a7);
            }
            float dot  = ((a0 + a1) + (a2 + a3)) + ((a4 + a5) + (a6 + a7));
            float dist = (rr - 2.0f * dot) + c2q[j];
            if (dist < best_d) { best_d = dist; best_j = j; }  // first-min tie-break
        }

        // gather chosen code (per-lane divergent, L2-resident);
        // replicate reference's exact f32 update sequence
        const float* q = cb + (size_t)best_j * DIM;
        float ls = 0.f;
        #pragma unroll
        for (int k = 0; k < DIM; k += 4) {
            float4 qv = *reinterpret_cast<const float4*>(q + k);
            float s0 = qv.x - r[k + 0];
            float s1 = qv.y - r[k + 1];
            float s2 = qv.z - r[k + 2];
            float s3 = qv.w - r[k + 3];
            ls = fmaf(s0, s0, ls); ls = fmaf(s1, s1, ls);
            ls = fmaf(s2, s2, ls); ls = fmaf(s3, s3, ls);
            float qs0 = r[k + 0] + s0;
            float qs1 = r[k + 1] + s1;
            float qs2 = r[k + 2] + s2;
            float qs3 = r[k + 3] + s3;
            r[k + 0] = r[k + 0] - qs0;
            r[k + 1] = r[k + 1] - qs1;
            r[k + 2] = r[k + 2] - qs2;
            r[k + 3] = r[k + 3] - qs3;
        }
        lossacc += ls;
        out_idx[(size_t)row * NQ + qi] = (float)best_j;
    }

    // x_q = x - r_final (telescoped; ulp-equal to sum of quant_st)
    #pragma unroll
    for (int k = 0; k < DIM; k += 4) {
        float4 xv = *reinterpret_cast<const float4*>(xrow + k);
        float4 o;
        o.x = xv.x - r[k + 0];
        o.y = xv.y - r[k + 1];
        o.z = xv.z - r[k + 2];
        o.w = xv.w - r[k + 3];
        *reinterpret_cast<float4*>(out_xq + (size_t)row * DIM + k) = o;
    }

    // loss reduction: wave shuffle -> LDS -> one f64 atomic per block
    #pragma unroll
    for (int off = 32; off > 0; off >>= 1) lossacc += __shfl_down(lossacc, off);
    __shared__ float wsum[4];
    if ((tid & 63) == 0) wsum[tid >> 6] = lossacc;
    __syncthreads();
    if (tid == 0) {
        double t = ((double)wsum[0] + (double)wsum[1]) +
                   ((double)wsum[2] + (double)wsum[3]);
        atomicAdd(loss_acc, t);
    }
}

__global__ void rvq_finalize(const double* __restrict__ loss_acc,
                             float* __restrict__ out_loss) {
    if (threadIdx.x == 0 && blockIdx.x == 0) {
        // mean_loss = 2 * sum(s^2) / (NQ*N*D) = sum / 67108864
        *out_loss = (float)(*loss_acc * (1.0 / 67108864.0));
    }
}

extern "C" void kernel_launch(void* const* d_in, const int* in_sizes, int n_in,
                              void* d_out, int out_size, void* d_ws, size_t ws_size,
                              hipStream_t stream) {
    const float* x  = (const float*)d_in[0];
    const float* cb = (const float*)d_in[1];
    const int N = in_sizes[0] / DIM;  // 262144

    double* loss_acc = (double*)d_ws;
    float*  c2       = (float*)((char*)d_ws + 256);

    float* out_xq   = (float*)d_out;
    float* out_loss = out_xq + (size_t)N * DIM;
    float* out_idx  = out_loss + 1;

    rvq_prep<<<(NQ * NE + 255) / 256, 256, 0, stream>>>(cb, loss_acc, c2);
    rvq_main<<<N / 256, 256, 0, stream>>>(x, cb, c2, out_xq, out_idx, loss_acc);
    rvq_finalize<<<1, 64, 0, stream>>>(loss_acc, out_loss);
}

// Round 3
// 2205.823 us; speedup vs baseline: 3.3428x; 3.1345x over previous
//
#include <hip/hip_runtime.h>
#include <stdint.h>

// ResidualVectorQuantizer: N=262144 rows, D=128, NQ=4 stages, NE=256 codes.
// Round 3: 2 threads/row (r[64] in VGPRs), codebook tiles double-buffered in
// LDS via global_load_lds with counted vmcnt (never 0 mid-loop), raw barriers.
// Inner loop: ds_read_b128 broadcast (2-way = free) + v_fma_f32, VALU-bound.

constexpr int DIM     = 128;
constexpr int NQ      = 4;
constexpr int NE      = 256;
constexpr int HALF    = 64;                    // dims per thread
constexpr int TCODES  = 32;                    // codes per LDS tile
constexpr int NTILES  = (NQ * NE) / TCODES;    // 32 tiles, contiguous across stages
constexpr int TILE_B  = TCODES * DIM * 4;      // 16384 bytes

// ws layout: [0,8) double loss accumulator; [256, 256+NQ*NE*4) c2 table.

__global__ __launch_bounds__(256) void rvq_prep(const float* __restrict__ codebooks,
                                                double* __restrict__ loss_acc,
                                                float* __restrict__ c2) {
    int g = blockIdx.x * blockDim.x + threadIdx.x;
    if (g == 0) *loss_acc = 0.0;
    if (g < NQ * NE) {
        const float* c = codebooks + (size_t)g * DIM;
        float s = 0.f;
        #pragma unroll 4
        for (int k = 0; k < DIM; ++k) s = fmaf(c[k], c[k], s);
        c2[g] = s;
    }
}

__device__ __forceinline__ void issue_tile(const float* __restrict__ cb,
                                           float* ldsbuf, int lane, int wv, int g) {
    // 16 KB tile, 4 waves x 4 global_load_lds_dwordx4 (1 KB each), linear LDS dest.
    const char* src = (const char*)cb + (size_t)g * TILE_B;
    char* dst = (char*)ldsbuf;
    #pragma unroll
    for (int i = 0; i < 4; ++i) {
        int off = (wv * 4 + i) * 1024;
        __builtin_amdgcn_global_load_lds(
            (const __attribute__((address_space(1))) uint32_t*)(src + off + lane * 16),
            (__attribute__((address_space(3))) uint32_t*)(dst + off),
            16, 0, 0);
    }
}

__global__ __launch_bounds__(256) void rvq_main(const float* __restrict__ x,
                                                const float* __restrict__ codebooks,
                                                const float* __restrict__ c2g,
                                                float* __restrict__ out_xq,
                                                float* __restrict__ out_idx,
                                                double* __restrict__ loss_acc) {
    __shared__ float tile[2][TCODES][DIM];   // 32 KB double buffer
    __shared__ float c2s[NQ * NE];           // 4 KB, loaded once
    __shared__ float wsum[4];

    const int tid  = threadIdx.x;
    const int lane = tid & 63;
    const int wv   = tid >> 6;

    #pragma unroll
    for (int i = 0; i < 4; ++i) c2s[tid + 256 * i] = c2g[tid + 256 * i];

    const int row  = blockIdx.x * 128 + (tid >> 1);
    const int half = tid & 1;
    const float* xrow = x + (size_t)row * DIM + half * HALF;

    float r[HALF];
    #pragma unroll
    for (int k = 0; k < HALF; k += 4) {
        float4 v = *reinterpret_cast<const float4*>(xrow + k);
        r[k] = v.x; r[k + 1] = v.y; r[k + 2] = v.z; r[k + 3] = v.w;
    }

    __syncthreads();                 // c2s visible; x loads drained
    issue_tile(codebooks, &tile[0][0][0], lane, wv, 0);   // prologue prefetch

    float lossacc = 0.f;

    #pragma unroll 1
    for (int qi = 0; qi < NQ; ++qi) {
        // rr = ||residual||^2 over full row (pair-sum; commutative -> bitwise equal)
        float rr0 = 0.f, rr1 = 0.f, rr2 = 0.f, rr3 = 0.f;
        #pragma unroll
        for (int k = 0; k < HALF; k += 4) {
            rr0 = fmaf(r[k + 0], r[k + 0], rr0);
            rr1 = fmaf(r[k + 1], r[k + 1], rr1);
            rr2 = fmaf(r[k + 2], r[k + 2], rr2);
            rr3 = fmaf(r[k + 3], r[k + 3], rr3);
        }
        float rr = (rr0 + rr1) + (rr2 + rr3);
        rr += __shfl_xor(rr, 1);

        float best_d = 3.4e38f;
        int   best_j = 0;

        #pragma unroll 1
        for (int t = 0; t < 8; ++t) {
            const int g = qi * 8 + t;
            // barrier A: everyone done reading the buffer tile g+1 will overwrite
            __builtin_amdgcn_s_barrier();
            if (g + 1 < NTILES) {
                issue_tile(codebooks, &tile[(g + 1) & 1][0][0], lane, wv, g + 1);
                asm volatile("s_waitcnt vmcnt(4)" ::: "memory");  // tile g landed; g+1 in flight
            } else {
                asm volatile("s_waitcnt vmcnt(0)" ::: "memory");
            }
            // barrier B: everyone's tile-g loads complete
            __builtin_amdgcn_s_barrier();

            const float (*tb)[DIM] = tile[g & 1];
            const float* c2t = &c2s[qi * NE + t * TCODES];

            #pragma unroll 1
            for (int j = 0; j < TCODES; ++j) {
                const float* cj = &tb[j][half * HALF];   // 2 addrs/wave: 2-way, free
                float a0 = 0.f, a1 = 0.f, a2 = 0.f, a3 = 0.f;
                #pragma unroll
                for (int k = 0; k < HALF; k += 4) {
                    float4 c4 = *reinterpret_cast<const float4*>(cj + k);
                    a0 = fmaf(c4.x, r[k + 0], a0);
                    a1 = fmaf(c4.y, r[k + 1], a1);
                    a2 = fmaf(c4.z, r[k + 2], a2);
                    a3 = fmaf(c4.w, r[k + 3], a3);
                }
                float dot = (a0 + a1) + (a2 + a3);
                dot += __shfl_xor(dot, 1);               // full-row dot, both lanes identical
                float dist = (rr - 2.0f * dot) + c2t[j];
                int jj = t * TCODES + j;
                if (dist < best_d) { best_d = dist; best_j = jj; }  // first-min tie-break
            }
        }

        // gather chosen code (divergent, L2-resident); exact reference f32 update order
        const float* q = codebooks + ((size_t)qi * NE + best_j) * DIM + half * HALF;
        float ls = 0.f;
        #pragma unroll
        for (int k = 0; k < HALF; k += 4) {
            float4 qv = *reinterpret_cast<const float4*>(q + k);
            float s0 = qv.x - r[k + 0];
            float s1 = qv.y - r[k + 1];
            float s2 = qv.z - r[k + 2];
            float s3 = qv.w - r[k + 3];
            ls = fmaf(s0, s0, ls); ls = fmaf(s1, s1, ls);
            ls = fmaf(s2, s2, ls); ls = fmaf(s3, s3, ls);
            float qs0 = r[k + 0] + s0;
            float qs1 = r[k + 1] + s1;
            float qs2 = r[k + 2] + s2;
            float qs3 = r[k + 3] + s3;
            r[k + 0] = r[k + 0] - qs0;
            r[k + 1] = r[k + 1] - qs1;
            r[k + 2] = r[k + 2] - qs2;
            r[k + 3] = r[k + 3] - qs3;
        }
        lossacc += ls;
        if (half == 0) out_idx[(size_t)row * NQ + qi] = (float)best_j;
    }

    // x_q = x - r_final (telescoped; ulp-equal to sum of quant_st)
    #pragma unroll
    for (int k = 0; k < HALF; k += 4) {
        float4 xv = *reinterpret_cast<const float4*>(xrow + k);
        float4 o;
        o.x = xv.x - r[k + 0];
        o.y = xv.y - r[k + 1];
        o.z = xv.z - r[k + 2];
        o.w = xv.w - r[k + 3];
        *reinterpret_cast<float4*>(out_xq + (size_t)row * DIM + half * HALF + k) = o;
    }

    // loss reduction: wave shuffle -> LDS -> one f64 atomic per block
    #pragma unroll
    for (int off = 32; off > 0; off >>= 1) lossacc += __shfl_down(lossacc, off);
    if ((tid & 63) == 0) wsum[tid >> 6] = lossacc;
    __syncthreads();
    if (tid == 0) {
        double tsum = ((double)wsum[0] + (double)wsum[1]) +
                      ((double)wsum[2] + (double)wsum[3]);
        atomicAdd(loss_acc, tsum);
    }
}

__global__ void rvq_finalize(const double* __restrict__ loss_acc,
                             float* __restrict__ out_loss) {
    if (threadIdx.x == 0 && blockIdx.x == 0) {
        // mean_loss = 2 * sum(s^2) / (NQ*N*D) = sum / 67108864
        *out_loss = (float)(*loss_acc * (1.0 / 67108864.0));
    }
}

extern "C" void kernel_launch(void* const* d_in, const int* in_sizes, int n_in,
                              void* d_out, int out_size, void* d_ws, size_t ws_size,
                              hipStream_t stream) {
    const float* x  = (const float*)d_in[0];
    const float* cb = (const float*)d_in[1];
    const int N = in_sizes[0] / DIM;  // 262144

    double* loss_acc = (double*)d_ws;
    float*  c2       = (float*)((char*)d_ws + 256);

    float* out_xq   = (float*)d_out;
    float* out_loss = out_xq + (size_t)N * DIM;
    float* out_idx  = out_loss + 1;

    rvq_prep<<<(NQ * NE + 255) / 256, 256, 0, stream>>>(cb, loss_acc, c2);
    rvq_main<<<N / 128, 256, 0, stream>>>(x, cb, c2, out_xq, out_idx, loss_acc);
    rvq_finalize<<<1, 64, 0, stream>>>(loss_acc, out_loss);
}

// Round 4
// 1513.528 us; speedup vs baseline: 4.8719x; 1.4574x over previous
//
#include <hip/hip_runtime.h>
#include <stdint.h>

// ResidualVectorQuantizer: N=262144 rows, D=128, NQ=4 stages, NE=256 codes.
// Round 4: 4 rows x 32 dims per lane (quad-of-lanes per row-set), r in 128
// VGPRs. Codebook tiles (32 codes) double-buffered in LDS with 576B/code
// padding (bank-conflict-free quarter reads), reg-staged (issue-early /
// write-late). Quad reduction via DPP quad_perm (VALU, not LDS pipe).
// Per wave-code: 8 ds_read_b128 + 128 FMA -> VALU-bound.

constexpr int DIM      = 128;
constexpr int NQ       = 4;
constexpr int NE       = 256;
constexpr int TCODES   = 32;                    // codes per LDS tile
constexpr int NTILES   = (NQ * NE) / TCODES;    // 32
constexpr int CODE_PAD = 576;                   // 512B data + 4x16B quarter pad
constexpr int TILE_PAD = TCODES * CODE_PAD;     // 18432 B
constexpr int TILE_RAW = TCODES * DIM * 4;      // 16384 B logical

// ws layout: [0,8) double loss accumulator; [256, 256+NQ*NE*4) c2 table.

__global__ __launch_bounds__(256) void rvq_prep(const float* __restrict__ codebooks,
                                                double* __restrict__ loss_acc,
                                                float* __restrict__ c2) {
    int g = blockIdx.x * blockDim.x + threadIdx.x;
    if (g == 0) *loss_acc = 0.0;
    if (g < NQ * NE) {
        const float* c = codebooks + (size_t)g * DIM;
        float s = 0.f;
        #pragma unroll 4
        for (int k = 0; k < DIM; ++k) s = fmaf(c[k], c[k], s);
        c2[g] = s;
    }
}

// quad butterfly add: after this, all 4 lanes of a quad hold the bitwise-
// identical sum of their 4 partials (commutative pairwise order).
__device__ __forceinline__ float quad_red(float x) {
    int a = __builtin_amdgcn_mov_dpp(__float_as_int(x), 0xB1, 0xF, 0xF, true); // quad_perm [1,0,3,2]
    x = x + __int_as_float(a);
    int b = __builtin_amdgcn_mov_dpp(__float_as_int(x), 0x4E, 0xF, 0xF, true); // quad_perm [2,3,0,1]
    return x + __int_as_float(b);
}

__global__ __launch_bounds__(256, 2) void rvq_main(const float* __restrict__ x,
                                                   const float* __restrict__ cb,
                                                   const float* __restrict__ c2g,
                                                   float* __restrict__ out_xq,
                                                   float* __restrict__ out_idx,
                                                   double* __restrict__ loss_acc) {
    __shared__ char tile[2][TILE_PAD];   // 36864 B
    __shared__ float wsum[4];

    const int tid  = threadIdx.x;
    const int lane = tid & 63;
    const int wv   = tid >> 6;
    const int q    = lane & 3;    // dim quarter (32 dims)
    const int grp  = lane >> 2;   // row group within wave

    const int row0 = blockIdx.x * 256 + wv * 64 + grp * 4;   // rows row0..row0+3
    const float* xbase = x + (size_t)row0 * DIM + q * 32;

    // staging maps: logical byte L in [0,16384) -> padded LDS offset
    int ls[4], ps[4];
    #pragma unroll
    for (int i = 0; i < 4; ++i) {
        int L = wv * 4096 + i * 1024 + lane * 16;
        ls[i] = L;
        int code = L >> 9, qq = (L >> 7) & 3, rem = L & 127;
        ps[i] = code * CODE_PAD + qq * 144 + rem;
    }

    // issue tile-0 staging loads (early)
    float4 sreg[4];
    #pragma unroll
    for (int i = 0; i < 4; ++i)
        sreg[i] = *(const float4*)((const char*)cb + ls[i]);

    // load this lane's 4 rows x 32 dims
    float r[4][32];
    #pragma unroll
    for (int m = 0; m < 4; ++m) {
        #pragma unroll
        for (int s = 0; s < 8; ++s) {
            float4 v = *(const float4*)(xbase + (size_t)m * DIM + s * 4);
            r[m][s * 4 + 0] = v.x; r[m][s * 4 + 1] = v.y;
            r[m][s * 4 + 2] = v.z; r[m][s * 4 + 3] = v.w;
        }
    }

    // write tile 0 into padded LDS
    #pragma unroll
    for (int i = 0; i < 4; ++i) *(float4*)(&tile[0][ps[i]]) = sreg[i];

    // rr = ||residual||^2 (quarter partial, quad butterfly -> identical in quad)
    float rr[4];
    #pragma unroll
    for (int m = 0; m < 4; ++m) {
        float p = 0.f;
        #pragma unroll
        for (int k = 0; k < 32; ++k) p = fmaf(r[m][k], r[m][k], p);
        rr[m] = quad_red(p);
    }

    __syncthreads();   // tile 0 visible

    float lossacc = 0.f;
    float best_d[4];
    int   bj[4];

    #pragma unroll 1
    for (int g = 0; g < NTILES; ++g) {
        const int qi = g >> 3;
        if ((g & 7) == 0) {
            #pragma unroll
            for (int m = 0; m < 4; ++m) { best_d[m] = 3.4e38f; bj[m] = 0; }
        }

        // issue next tile's staging loads early (land during compute)
        if (g + 1 < NTILES) {
            #pragma unroll
            for (int i = 0; i < 4; ++i)
                sreg[i] = *(const float4*)((const char*)cb +
                                           (size_t)(g + 1) * TILE_RAW + ls[i]);
        }

        // ---- compute tile g: 32 codes ----
        const char* tb = &tile[g & 1][q * 144];
        const int jbase = (g & 7) * TCODES;
        const float* c2q = c2g + (qi << 8) + jbase;   // uniform -> scalar loads

        #pragma unroll 2
        for (int j = 0; j < TCODES; ++j) {
            const float4* cp = (const float4*)(tb + j * CODE_PAD);
            float4 c[8];
            #pragma unroll
            for (int i = 0; i < 8; ++i) c[i] = cp[i];
            float dot[4] = {0.f, 0.f, 0.f, 0.f};
            #pragma unroll
            for (int i = 0; i < 8; ++i) {
                #pragma unroll
                for (int m = 0; m < 4; ++m) {
                    dot[m] = fmaf(c[i].x, r[m][i * 4 + 0], dot[m]);
                    dot[m] = fmaf(c[i].y, r[m][i * 4 + 1], dot[m]);
                    dot[m] = fmaf(c[i].z, r[m][i * 4 + 2], dot[m]);
                    dot[m] = fmaf(c[i].w, r[m][i * 4 + 3], dot[m]);
                }
            }
            float c2j = c2q[j];
            #pragma unroll
            for (int m = 0; m < 4; ++m) {
                float d    = quad_red(dot[m]);             // full dot, quad-identical
                float dist = (rr[m] - 2.0f * d) + c2j;
                if (dist < best_d[m]) { best_d[m] = dist; bj[m] = jbase + j; }
            }
        }

        // ---- stage write (late) ----
        if (g + 1 < NTILES) {
            __syncthreads();   // barrier A: all done reading buf[(g+1)&1]
            #pragma unroll
            for (int i = 0; i < 4; ++i)
                *(float4*)(&tile[(g + 1) & 1][ps[i]]) = sreg[i];
            __syncthreads();   // barrier B: tile g+1 visible
        }

        // ---- per-stage update ----
        if ((g & 7) == 7) {
            #pragma unroll
            for (int m = 0; m < 4; ++m) {
                const float* qb = cb + ((size_t)(qi << 8) + bj[m]) * DIM + q * 32;
                float4 qv[8];
                #pragma unroll
                for (int s = 0; s < 8; ++s) qv[s] = *(const float4*)(qb + s * 4);
                #pragma unroll
                for (int s = 0; s < 8; ++s) {
                    float e0 = qv[s].x - r[m][s * 4 + 0];
                    float e1 = qv[s].y - r[m][s * 4 + 1];
                    float e2 = qv[s].z - r[m][s * 4 + 2];
                    float e3 = qv[s].w - r[m][s * 4 + 3];
                    lossacc = fmaf(e0, e0, lossacc); lossacc = fmaf(e1, e1, lossacc);
                    lossacc = fmaf(e2, e2, lossacc); lossacc = fmaf(e3, e3, lossacc);
                    // reference's exact f32 straight-through sequence
                    float qs0 = r[m][s * 4 + 0] + e0;
                    float qs1 = r[m][s * 4 + 1] + e1;
                    float qs2 = r[m][s * 4 + 2] + e2;
                    float qs3 = r[m][s * 4 + 3] + e3;
                    r[m][s * 4 + 0] = r[m][s * 4 + 0] - qs0;
                    r[m][s * 4 + 1] = r[m][s * 4 + 1] - qs1;
                    r[m][s * 4 + 2] = r[m][s * 4 + 2] - qs2;
                    r[m][s * 4 + 3] = r[m][s * 4 + 3] - qs3;
                }
            }
            if (qi < NQ - 1) {   // rr for next stage
                #pragma unroll
                for (int m = 0; m < 4; ++m) {
                    float p = 0.f;
                    #pragma unroll
                    for (int k = 0; k < 32; ++k) p = fmaf(r[m][k], r[m][k], p);
                    rr[m] = quad_red(p);
                }
            }
            if (q == 0) {
                #pragma unroll
                for (int m = 0; m < 4; ++m)
                    out_idx[(size_t)(row0 + m) * NQ + qi] = (float)bj[m];
            }
        }
    }

    // x_q = x - r_final (telescoped; ulp-equal to sum of quant_st)
    #pragma unroll
    for (int m = 0; m < 4; ++m) {
        #pragma unroll
        for (int s = 0; s < 8; ++s) {
            float4 xv = *(const float4*)(xbase + (size_t)m * DIM + s * 4);
            float4 o;
            o.x = xv.x - r[m][s * 4 + 0];
            o.y = xv.y - r[m][s * 4 + 1];
            o.z = xv.z - r[m][s * 4 + 2];
            o.w = xv.w - r[m][s * 4 + 3];
            *(float4*)(out_xq + (size_t)(row0 + m) * DIM + q * 32 + s * 4) = o;
        }
    }

    // loss reduction: wave shuffle -> LDS -> one f64 atomic per block
    #pragma unroll
    for (int off = 32; off > 0; off >>= 1) lossacc += __shfl_down(lossacc, off);
    if (lane == 0) wsum[wv] = lossacc;
    __syncthreads();
    if (tid == 0) {
        double t = ((double)wsum[0] + (double)wsum[1]) +
                   ((double)wsum[2] + (double)wsum[3]);
        atomicAdd(loss_acc, t);
    }
}

__global__ void rvq_finalize(const double* __restrict__ loss_acc,
                             float* __restrict__ out_loss) {
    if (threadIdx.x == 0 && blockIdx.x == 0) {
        // mean_loss = 2 * sum(s^2) / (NQ*N*D) = sum / 67108864
        *out_loss = (float)(*loss_acc * (1.0 / 67108864.0));
    }
}

extern "C" void kernel_launch(void* const* d_in, const int* in_sizes, int n_in,
                              void* d_out, int out_size, void* d_ws, size_t ws_size,
                              hipStream_t stream) {
    const float* x  = (const float*)d_in[0];
    const float* cb = (const float*)d_in[1];
    const int N = in_sizes[0] / DIM;  // 262144

    double* loss_acc = (double*)d_ws;
    float*  c2       = (float*)((char*)d_ws + 256);

    float* out_xq   = (float*)d_out;
    float* out_loss = out_xq + (size_t)N * DIM;
    float* out_idx  = out_loss + 1;

    rvq_prep<<<(NQ * NE + 255) / 256, 256, 0, stream>>>(cb, loss_acc, c2);
    rvq_main<<<N / 256, 256, 0, stream>>>(x, cb, c2, out_xq, out_idx, loss_acc);
    rvq_finalize<<<1, 64, 0, stream>>>(loss_acc, out_loss);
}